// Round 7
// baseline (312.456 us; speedup 1.0000x reference)
//
#include <hip/hip_runtime.h>
#include <math.h>

#define YAT_EPS (1.0f / 137.0f)

// Logical sizes (fixed): B=2, T=1024, C=1024.
// Attention (faithful to reference transpose): 64 "heads" (d axis),
// per-head dim 16 (h axis), causal, T=1024.
// qkvT layout: [b][s][d][h][t]  (t contiguous; plane of 16384 per (b,s,d))

typedef __bf16 bf16x8 __attribute__((ext_vector_type(8)));
typedef float floatx4 __attribute__((ext_vector_type(4)));

__device__ __forceinline__ float fast_rcp(float x) {
#if __has_builtin(__builtin_amdgcn_rcpf)
    return __builtin_amdgcn_rcpf(x);
#else
    return 1.0f / x;
#endif
}
__device__ __forceinline__ float fast_exp2(float x) {
#if __has_builtin(__builtin_amdgcn_exp2f)
    return __builtin_amdgcn_exp2f(x);
#else
    return exp2f(x);
#endif
}

__device__ __forceinline__ unsigned short f32_bf16(float f) {
    unsigned u = __builtin_bit_cast(unsigned, f);
    u += 0x7fffu + ((u >> 16) & 1u);      // RNE; inputs are finite/normal
    return (unsigned short)(u >> 16);
}
__device__ __forceinline__ float bf16_f32(unsigned short h) {
    unsigned u = ((unsigned)h) << 16;
    return __builtin_bit_cast(float, u);
}

// ---------------------------------------------------------------------------
// Fused: W[K][N] fp32 -> Wt hi/lo [N][K] bf16  +  k2[n] = sum_k W[k][n]^2
// ---------------------------------------------------------------------------
__global__ void convtrans_kernel(
    const float* __restrict__ W, unsigned short* __restrict__ th,
    unsigned short* __restrict__ tl, float* __restrict__ k2, int K, int N)
{
    __shared__ float t[32][33];
    int tx = threadIdx.x, ty = threadIdx.y;
    int n0 = blockIdx.x * 32, k0 = blockIdx.y * 32;
    #pragma unroll
    for (int r = 0; r < 4; ++r)
        t[ty + r * 8][tx] = W[(size_t)(k0 + ty + r * 8) * N + n0 + tx];
    __syncthreads();
    #pragma unroll
    for (int r = 0; r < 4; ++r) {
        int nl = ty + r * 8;
        float v = t[tx][nl];
        unsigned short h = f32_bf16(v);
        th[(size_t)(n0 + nl) * K + k0 + tx] = h;
        tl[(size_t)(n0 + nl) * K + k0 + tx] = f32_bf16(v - bf16_f32(h));
        float s = v * v;
        #pragma unroll
        for (int m = 16; m > 0; m >>= 1) s += __shfl_xor(s, m, 32);
        if (tx == 0) atomicAdd(&k2[n0 + nl], s);
    }
}

// ---------------------------------------------------------------------------
// Fused: x row -> bf16 hi/lo + x2[row].  One block (256 thr) per 1024-f row.
// ---------------------------------------------------------------------------
__global__ __launch_bounds__(256) void convx_kernel(
    const float* __restrict__ x, unsigned short* __restrict__ hi,
    unsigned short* __restrict__ lo, float* __restrict__ x2x)
{
    __shared__ float red[4];
    const int row = blockIdx.x, tid = threadIdx.x;
    float4 v = *(const float4*)(x + (size_t)row * 1024 + tid * 4);
    float vv[4] = {v.x, v.y, v.z, v.w};
    unsigned short hh[4], ll[4];
    float s = 0.0f;
    #pragma unroll
    for (int e = 0; e < 4; ++e) {
        hh[e] = f32_bf16(vv[e]);
        ll[e] = f32_bf16(vv[e] - bf16_f32(hh[e]));
        s = fmaf(vv[e], vv[e], s);
    }
    *(ushort4*)(hi + (size_t)row * 1024 + tid * 4) =
        make_ushort4(hh[0], hh[1], hh[2], hh[3]);
    *(ushort4*)(lo + (size_t)row * 1024 + tid * 4) =
        make_ushort4(ll[0], ll[1], ll[2], ll[3]);
    #pragma unroll
    for (int off = 32; off > 0; off >>= 1) s += __shfl_down(s, off, 64);
    if ((tid & 63) == 0) red[tid >> 6] = s;
    __syncthreads();
    if (tid == 0) x2x[row] = red[0] + red[1] + red[2] + red[3];
}

// ---------------------------------------------------------------------------
// k2k[b][d][t] = sum_h K[b][d][h][t]^2 over the K planes of qkvT
// ---------------------------------------------------------------------------
__global__ __launch_bounds__(256) void sumsq16_kernel(
    const float* __restrict__ qkvT, float* __restrict__ k2k)
{
    int idx = blockIdx.x * 256 + threadIdx.x;   // b*65536 + d*1024 + t
    int b = idx >> 16;
    int d = (idx >> 10) & 63;
    int t = idx & 1023;
    const float* pl = qkvT + ((size_t)((b * 3 + 1) * 64 + d)) * 16384 + t;
    float s = 0.0f;
    #pragma unroll
    for (int h = 0; h < 16; ++h) {
        float v = pl[h * 1024];
        s = fmaf(v, v, s);
    }
    k2k[idx] = s;
}

// ---------------------------------------------------------------------------
// Split-bf16 MFMA YAT-dense GEMM, templated m-tile.
// BM=64 for both GEMMs (768 / 256 blocks — BM=128 starved the grid, R6).
// ---------------------------------------------------------------------------
template <int BM, int MODE>
__global__ __launch_bounds__(256) void gemm_yat_mfma_kernel(
    const unsigned short* __restrict__ Ah, const unsigned short* __restrict__ Al,
    const unsigned short* __restrict__ Bh, const unsigned short* __restrict__ Bl,
    const float* __restrict__ bias, const float* __restrict__ x2,
    const float* __restrict__ k2, const float* __restrict__ alphap,
    float* __restrict__ out, int N, int K, float scale_base)
{
    constexpr int TM = BM / 32;
    constexpr int NI = (BM * 128 + 16384) / 4096;
    __shared__ __align__(16) unsigned short sbuf[BM * 64 + 8192];

    const int tid = threadIdx.x;
    const int w = tid >> 6, l = tid & 63;
    const int lane16 = l & 15, quad = l >> 4;
    const int wm = w & 1, wn = w >> 1;
    const int m0 = blockIdx.y * BM, n0 = blockIdx.x * 128;

    floatx4 acc[TM][4];
    #pragma unroll
    for (int tm = 0; tm < TM; ++tm)
        #pragma unroll
        for (int tn = 0; tn < 4; ++tn)
            acc[tm][tn] = (floatx4){0.f, 0.f, 0.f, 0.f};

    for (int k0 = 0; k0 < K; k0 += 32) {
        __syncthreads();
        #pragma unroll
        for (int i = 0; i < NI; ++i) {
            const int o = (i * 4 + w) * 1024;
            const unsigned short* gp;
            if (o < BM * 128) {
                const unsigned short* g = (o < BM * 64) ? Ah : Al;
                const int oo = (o < BM * 64) ? o : o - BM * 64;
                gp = g + (size_t)(m0 + (oo >> 6) + (l >> 2)) * K + k0 + (l & 3) * 8;
            } else {
                const int ob = o - BM * 128;
                const unsigned short* g = (ob < 8192) ? Bh : Bl;
                const int oo = ob & 8191;
                gp = g + (size_t)(n0 + (oo >> 6) + (l >> 2)) * K + k0 + (l & 3) * 8;
            }
            __builtin_amdgcn_global_load_lds(
                (const __attribute__((address_space(1))) unsigned int*)gp,
                (__attribute__((address_space(3))) unsigned int*)((char*)sbuf + o),
                16, 0, 0);
        }
        __syncthreads();

        bf16x8 afh[TM], afl[TM], bfh[4], bfl[4];
        #pragma unroll
        for (int tm = 0; tm < TM; ++tm) {
            const int base = (wm * (BM / 2) + tm * 16 + lane16) * 32 + quad * 8;
            afh[tm] = *(const bf16x8*)(sbuf + base);
            afl[tm] = *(const bf16x8*)(sbuf + BM * 32 + base);
        }
        #pragma unroll
        for (int tn = 0; tn < 4; ++tn) {
            const int nb = (wn * 64 + tn * 16 + lane16) * 32 + quad * 8;
            bfh[tn] = *(const bf16x8*)(sbuf + BM * 64 + nb);
            bfl[tn] = *(const bf16x8*)(sbuf + BM * 64 + 4096 + nb);
        }
        #pragma unroll
        for (int tm = 0; tm < TM; ++tm)
            #pragma unroll
            for (int tn = 0; tn < 4; ++tn) {
                acc[tm][tn] = __builtin_amdgcn_mfma_f32_16x16x32_bf16(
                    afh[tm], bfh[tn], acc[tm][tn], 0, 0, 0);
                acc[tm][tn] = __builtin_amdgcn_mfma_f32_16x16x32_bf16(
                    afh[tm], bfl[tn], acc[tm][tn], 0, 0, 0);
                acc[tm][tn] = __builtin_amdgcn_mfma_f32_16x16x32_bf16(
                    afl[tm], bfh[tn], acc[tm][tn], 0, 0, 0);
            }
    }

    const float scale = powf(scale_base, alphap[0]);
    #pragma unroll
    for (int tm = 0; tm < TM; ++tm) {
        #pragma unroll
        for (int tn = 0; tn < 4; ++tn) {
            const int n = n0 + wn * 64 + tn * 16 + lane16;
            const float kk = k2[n];
            const float bb = bias[n];
            const int mrow = m0 + wm * (BM / 2) + tm * 16 + quad * 4;
            float4 r4;
            float* rp = (float*)&r4;
            #pragma unroll
            for (int r = 0; r < 4; ++r) {
                const float y = acc[tm][tn][r];
                const float den = x2[mrow + r] + kk - 2.0f * y + YAT_EPS;
                rp[r] = y * y / den * scale + bb;
            }
            if (MODE == 0) {
                #pragma unroll
                for (int r = 0; r < 4; ++r)
                    out[(size_t)(mrow + r) * N + n] = rp[r];
            } else {
                const int s = n >> 10, hh = (n >> 6) & 15, dd = n & 63;
                const int bb2 = m0 >> 10;
                const int t0 = (mrow & 1023);
                *(float4*)&out[((size_t)((bb2 * 3 + s) * 64 + dd) * 16 + hh)
                               * 1024 + t0] = r4;
            }
        }
    }
}

// ---------------------------------------------------------------------------
// Attention v6: 4 rows/lane.  Block = one (g,d,b): 4 waves = 4 j-quarters
// (private LDS tile + private softmax state; no main-loop barriers).
// Wave rows/lane from balanced tile group {15-g, 8+g, 7-g, g} (sum 34 for
// every g).  Active rows for j-tile jt form a prefix NR(jt) in {4,3,2,1}
// (tiles sorted descending) -> templated inner loop.
// Grid = 4 x 64 x 2 = 512 blocks.
// ---------------------------------------------------------------------------
template <int NR>
__device__ __forceinline__ void yat_tile_n(
    const float* __restrict__ kT, const float* __restrict__ vT,
    const float* __restrict__ k2T, int j0, const int (&iR)[4],
    const float (&qr)[4][16], const float (&q2e)[4], float inv_scale,
    float (&mm)[4], float (&ll)[4], float (&orr)[4][16])
{
    #pragma unroll 2
    for (int jj = 0; jj < 64; ++jj) {
        const int j = j0 + jj;
        const float* kp = kT + jj * 16;
        const float* vp = vT + jj * 16;
        float kr[16], vr[16];
        #pragma unroll
        for (int h4 = 0; h4 < 4; ++h4) {
            float4 kv = *(const float4*)(kp + h4 * 4);
            float4 vv = *(const float4*)(vp + h4 * 4);
            kr[h4*4+0] = kv.x; kr[h4*4+1] = kv.y;
            kr[h4*4+2] = kv.z; kr[h4*4+3] = kv.w;
            vr[h4*4+0] = vv.x; vr[h4*4+1] = vv.y;
            vr[h4*4+2] = vv.z; vr[h4*4+3] = vv.w;
        }
        const float kk2 = k2T[jj];

        float dot[NR];
        #pragma unroll
        for (int r = 0; r < NR; ++r) {
            float dd = 0.0f;
            #pragma unroll
            for (int h = 0; h < 16; ++h) dd = fmaf(qr[r][h], kr[h], dd);
            dot[r] = dd;
        }
        #pragma unroll
        for (int r = 0; r < NR; ++r) {
            const float den = q2e[r] + kk2 - 2.0f * dot[r];
            float s = dot[r] * dot[r] * fast_rcp(den) * inv_scale;
            const bool ok = (j <= iR[r]);
            s = ok ? s : 0.0f;
            if (s > mm[r]) {
                const float mn = s + 30.0f;
                const float c = fast_exp2(mm[r] - mn);
                mm[r] = mn; ll[r] *= c;
                #pragma unroll
                for (int h = 0; h < 16; ++h) orr[r][h] *= c;
            }
            float p = fast_exp2(s - mm[r]);
            p = ok ? p : 0.0f;
            ll[r] += p;
            #pragma unroll
            for (int h = 0; h < 16; ++h) orr[r][h] = fmaf(p, vr[h], orr[r][h]);
        }
    }
}

__device__ __forceinline__ void write_row_hl(
    unsigned short* __restrict__ ah, unsigned short* __restrict__ al,
    float* __restrict__ x2a, int rowidx, size_t off,
    const float (&o)[16], float il)
{
    unsigned short hb[16], lb16[16];
    float s2 = 0.0f;
    #pragma unroll
    for (int h = 0; h < 16; ++h) {
        float v = o[h] * il;
        unsigned short hh = f32_bf16(v);
        hb[h] = hh;
        lb16[h] = f32_bf16(v - bf16_f32(hh));
        s2 = fmaf(v, v, s2);
    }
    #pragma unroll
    for (int q = 0; q < 4; ++q) {
        *(ushort4*)(ah + off + q * 4) =
            make_ushort4(hb[q*4], hb[q*4+1], hb[q*4+2], hb[q*4+3]);
        *(ushort4*)(al + off + q * 4) =
            make_ushort4(lb16[q*4], lb16[q*4+1], lb16[q*4+2], lb16[q*4+3]);
    }
    atomicAdd(&x2a[rowidx], s2);
}

__global__ __launch_bounds__(256, 2) void yat_attention6_kernel(
    const float* __restrict__ qkvT, const float* __restrict__ k2k,
    const float* __restrict__ alphap,
    unsigned short* __restrict__ attn_h, unsigned short* __restrict__ attn_l,
    float* __restrict__ x2a)
{
    // per-wave region: ktile 1024 f | vtile 1024 f | k2tile 64 f = 2112 f
    // merge buffer (3*64*18 = 3456 f) aliases tile regions post-barrier
    __shared__ __align__(16) float smem[8448];

    const int tid  = threadIdx.x;
    const int lane = tid & 63;
    const int q    = tid >> 6;          // j-quarter 0..3
    const int g    = blockIdx.x;        // 0..3 tile-group
    const int d    = blockIdx.y;        // 0..63
    const int b    = blockIdx.z;

    // tiles descending: active rows for any jt are a prefix
    const int tiles[4] = {15 - g, 8 + g, 7 - g, g};
    int iR[4];
    #pragma unroll
    for (int r = 0; r < 4; ++r) iR[r] = tiles[r] * 64 + lane;
    const int maxtile = 15 - g;

    const float inv_scale =
        powf(64.0f / log1pf(64.0f), alphap[0]) * 1.44269504f;

    const size_t plane = 16384;
    const float* qpl = qkvT + (size_t)((b * 3 + 0) * 64 + d) * plane;
    const float* kpl = qkvT + (size_t)((b * 3 + 1) * 64 + d) * plane;
    const float* vpl = qkvT + (size_t)((b * 3 + 2) * 64 + d) * plane;
    const float* k2row = k2k + ((size_t)b << 16) + ((size_t)d << 10);

    float* ktile  = smem + q * 2112;
    float* vtile  = ktile + 1024;
    float* k2tile = vtile + 1024;

    float qr[4][16], q2e[4];
    #pragma unroll
    for (int r = 0; r < 4; ++r) {
        float s2 = YAT_EPS;
        #pragma unroll
        for (int h = 0; h < 16; ++h) {
            qr[r][h] = qpl[h * 1024 + iR[r]];
            s2 = fmaf(qr[r][h], qr[r][h], s2);
        }
        q2e[r] = s2;
    }

    float mm[4] = {-1e30f, -1e30f, -1e30f, -1e30f};
    float ll[4] = {0.0f, 0.0f, 0.0f, 0.0f};
    float orr[4][16];
    #pragma unroll
    for (int r = 0; r < 4; ++r)
        #pragma unroll
        for (int h = 0; h < 16; ++h) orr[r][h] = 0.0f;

    for (int jt = q; jt <= maxtile; jt += 4) {
        const int j0 = jt * 64;
        // stage: lane <-> row j0+lane; 16 coalesced loads per array,
        // then 4 ds_write_b128 per array (2-way banks = free)
        float kr0[16], vr0[16];
        #pragma unroll
        for (int h = 0; h < 16; ++h) {
            kr0[h] = kpl[h * 1024 + j0 + lane];
            vr0[h] = vpl[h * 1024 + j0 + lane];
        }
        #pragma unroll
        for (int h4 = 0; h4 < 4; ++h4) {
            *(float4*)(ktile + lane * 16 + h4 * 4) = make_float4(
                kr0[h4*4], kr0[h4*4+1], kr0[h4*4+2], kr0[h4*4+3]);
            *(float4*)(vtile + lane * 16 + h4 * 4) = make_float4(
                vr0[h4*4], vr0[h4*4+1], vr0[h4*4+2], vr0[h4*4+3]);
        }
        k2tile[lane] = k2row[j0 + lane];
        // wave-private LDS: compiler inserts lgkm wait; no barrier needed
        const int NR = (jt <= g) ? 4 : (jt <= 7 - g) ? 3
                     : (jt <= 8 + g) ? 2 : 1;
        switch (NR) {
        case 4: yat_tile_n<4>(ktile, vtile, k2tile, j0, iR, qr, q2e,
                              inv_scale, mm, ll, orr); break;
        case 3: yat_tile_n<3>(ktile, vtile, k2tile, j0, iR, qr, q2e,
                              inv_scale, mm, ll, orr); break;
        case 2: yat_tile_n<2>(ktile, vtile, k2tile, j0, iR, qr, q2e,
                              inv_scale, mm, ll, orr); break;
        default: yat_tile_n<1>(ktile, vtile, k2tile, j0, iR, qr, q2e,
                               inv_scale, mm, ll, orr); break;
        }
    }

    // ---- merge 4 quarters, one row at a time (small LDS footprint) ----
    for (int r = 0; r < 4; ++r) {
        __syncthreads();
        if (q > 0) {
            float* mb = smem + ((q - 1) * 64 + lane) * 18;
            #pragma unroll
            for (int h = 0; h < 16; ++h) mb[h] = orr[r][h];
            mb[16] = mm[r]; mb[17] = ll[r];
        }
        __syncthreads();
        if (q == 0) {
            #pragma unroll
            for (int qq = 0; qq < 3; ++qq) {
                const float* mb = smem + (qq * 64 + lane) * 18;
                const float m1 = mb[16], l1 = mb[17];
                const float m = fmaxf(mm[r], m1);
                const float c0 = fast_exp2(mm[r] - m), c1 = fast_exp2(m1 - m);
                ll[r] = ll[r] * c0 + l1 * c1;
                #pragma unroll
                for (int h = 0; h < 16; ++h)
                    orr[r][h] = orr[r][h] * c0 + mb[h] * c1;
                mm[r] = m;
            }
        }
    }
    if (q == 0) {
        #pragma unroll
        for (int r = 0; r < 4; ++r) {
            const int rowidx = b * 1024 + iR[r];
            write_row_hl(attn_h, attn_l, x2a, rowidx,
                         (size_t)rowidx * 1024 + d * 16, orr[r],
                         1.0f / ll[r]);
        }
    }
}

// ---------------------------------------------------------------------------
extern "C" void kernel_launch(void* const* d_in, const int* in_sizes, int n_in,
                              void* d_out, int out_size, void* d_ws, size_t ws_size,
                              hipStream_t stream)
{
    const float* x          = (const float*)d_in[0];
    // d_in[1] = causal mask, constant — causality hard-coded
    const float* w_qkv      = (const float*)d_in[2];
    const float* b_qkv      = (const float*)d_in[3];
    const float* alpha_qkv  = (const float*)d_in[4];
    const float* w_proj     = (const float*)d_in[5];
    const float* b_proj     = (const float*)d_in[6];
    const float* alpha_proj = (const float*)d_in[7];
    const float* alpha_attn = (const float*)d_in[8];
    float* out = (float*)d_out;

    float* ws = (float*)d_ws;
    float*          qkvT = ws;                                   // 6291456
    unsigned short* WtQh = (unsigned short*)(ws + 6291456);      // 3072x1024 bf16
    unsigned short* WtQl = (unsigned short*)(ws + 7864320);
    unsigned short* WtPh = (unsigned short*)(ws + 9437184);      // 1024x1024 bf16
    unsigned short* WtPl = (unsigned short*)(ws + 9961472);
    unsigned short* xh   = (unsigned short*)(ws + 10485760);     // 2048x1024 bf16
    unsigned short* xl   = (unsigned short*)(ws + 11534336);
    float* x2x  = ws + 12582912;   // 2048
    float* x2a  = ws + 12584960;   // 2048 (atomic)
    float* k2q  = ws + 12587008;   // 3072 (atomic)
    float* k2p  = ws + 12590080;   // 1024 (atomic)
    float* k2k  = ws + 12591104;   // 131072
    unsigned short* attn_h = WtQh;  // alias: WtQ dead after QKV GEMM
    unsigned short* attn_l = WtQl;

    hipMemsetAsync(x2a, 0, (2048 + 3072 + 1024) * sizeof(float), stream);

    convtrans_kernel<<<dim3(96, 32), dim3(32, 8), 0, stream>>>(
        w_qkv, WtQh, WtQl, k2q, 1024, 3072);
    convtrans_kernel<<<dim3(32, 32), dim3(32, 8), 0, stream>>>(
        w_proj, WtPh, WtPl, k2p, 1024, 1024);
    convx_kernel<<<2048, 256, 0, stream>>>(x, xh, xl, x2x);

    const float sb_qkv = sqrtf(3072.0f) / log1pf(3072.0f);
    gemm_yat_mfma_kernel<64, 1><<<dim3(24, 32), 256, 0, stream>>>(
        xh, xl, WtQh, WtQl, b_qkv, x2x, k2q, alpha_qkv, qkvT,
        3072, 1024, sb_qkv);

    sumsq16_kernel<<<512, 256, 0, stream>>>(qkvT, k2k);

    yat_attention6_kernel<<<dim3(4, 64, 2), 256, 0, stream>>>(
        qkvT, k2k, alpha_attn, attn_h, attn_l, x2a);

    const float sb_proj = sqrtf(1024.0f) / log1pf(1024.0f);
    gemm_yat_mfma_kernel<64, 0><<<dim3(8, 32), 256, 0, stream>>>(
        attn_h, attn_l, WtPh, WtPl, b_proj, x2a, k2p, alpha_proj, out,
        1024, 1024, sb_proj);
}